// Round 1
// baseline (254.525 us; speedup 1.0000x reference)
//
#include <hip/hip_runtime.h>

// Problem shape (fixed by setup_inputs)
constexpr int Bn = 256;
constexpr int Tn = 10;
constexpr int Fn = 16384;
constexpr int FQ = Fn / 4;   // float4 strips per row = 4096 (power of 2)

// Fully fused: 3x LIF-box scan over T + 1x1 conv channel-sum + time-linear.
// One thread owns 4 consecutive f's for one b: 10 float4 loads, 2 float4 stores.
__global__ __launch_bounds__(256) void lif_net_kernel(
    const float* __restrict__ x,
    const float* __restrict__ p_tau1, const float* __restrict__ p_tau2,
    const float* __restrict__ p_tau3,
    const float* __restrict__ p_vth1, const float* __restrict__ p_vth2,
    const float* __restrict__ p_vth3,
    const float* __restrict__ conv_w, const float* __restrict__ conv_b,
    const float* __restrict__ lin_w,  const float* __restrict__ lin_b,
    float* __restrict__ out)
{
    // Uniform scalar params (compiler emits s_loads; L2-resident)
    const float k1 = __fmul_rn(0.001f, p_tau1[0]);   // DT * tau_inv, f32 single-rounded
    const float k2 = __fmul_rn(0.001f, p_tau2[0]);
    const float k3 = __fmul_rn(0.001f, p_tau3[0]);
    const float th1 = p_vth1[0], th2 = p_vth2[0], th3 = p_vth3[0];
    const float w0 = conv_w[0], w1 = conv_w[1], w2 = conv_w[2];
    const float cb = conv_b[0];
    const float lb0 = lin_b[0], lb1 = lin_b[1];

    const int idx = blockIdx.x * blockDim.x + threadIdx.x;  // 0 .. Bn*FQ-1
    const int b   = idx >> 12;        // idx / FQ
    const int fq  = idx & (FQ - 1);   // idx % FQ

    const float4* xp = reinterpret_cast<const float4*>(x + (size_t)b * Tn * Fn);

    float v1[4] = {0.f, 0.f, 0.f, 0.f};
    float v2[4] = {0.f, 0.f, 0.f, 0.f};
    float v3[4] = {0.f, 0.f, 0.f, 0.f};
    float a0[4] = {0.f, 0.f, 0.f, 0.f};
    float a1[4] = {0.f, 0.f, 0.f, 0.f};

#pragma unroll
    for (int t = 0; t < Tn; ++t) {
        const float4 xv = xp[fq + t * FQ];
        const float xs[4] = {xv.x, xv.y, xv.z, xv.w};
        const float lw0 = lin_w[t];        // lin_w[0][t]
        const float lw1 = lin_w[Tn + t];   // lin_w[1][t]
#pragma unroll
        for (int j = 0; j < 4; ++j) {
            // v_dec = v + k*(x - v); exact IEEE mul/add order, no contraction
            const float vd1 = __fadd_rn(v1[j], __fmul_rn(k1, __fsub_rn(xs[j], v1[j])));
            const bool  z1  = (__fsub_rn(vd1, th1) > 0.0f);
            v1[j] = z1 ? 0.0f : vd1;

            const float vd2 = __fadd_rn(v2[j], __fmul_rn(k2, __fsub_rn(xs[j], v2[j])));
            const bool  z2  = (__fsub_rn(vd2, th2) > 0.0f);
            v2[j] = z2 ? 0.0f : vd2;

            const float vd3 = __fadd_rn(v3[j], __fmul_rn(k3, __fsub_rn(xs[j], v3[j])));
            const bool  z3  = (__fsub_rn(vd3, th3) > 0.0f);
            v3[j] = z3 ? 0.0f : vd3;

            // y = ((w0*z1 + w1*z2) + w2*z3) + cb  (z in {0,1} -> exact products)
            float y = z1 ? w0 : 0.0f;
            y = __fadd_rn(y, z2 ? w1 : 0.0f);
            y = __fadd_rn(y, z3 ? w2 : 0.0f);
            y = __fadd_rn(y, cb);

            // time-linear accumulation (smooth; fma is fine)
            a0[j] = fmaf(y, lw0, a0[j]);
            a1[j] = fmaf(y, lw1, a1[j]);
        }
    }

    float* ob = out + (size_t)b * 2 * Fn;
    float4 o0, o1;
    o0.x = __fadd_rn(a0[0], lb0); o0.y = __fadd_rn(a0[1], lb0);
    o0.z = __fadd_rn(a0[2], lb0); o0.w = __fadd_rn(a0[3], lb0);
    o1.x = __fadd_rn(a1[0], lb1); o1.y = __fadd_rn(a1[1], lb1);
    o1.z = __fadd_rn(a1[2], lb1); o1.w = __fadd_rn(a1[3], lb1);
    reinterpret_cast<float4*>(ob)[fq]      = o0;   // [b, 0, f]
    reinterpret_cast<float4*>(ob + Fn)[fq] = o1;   // [b, 1, f]
}

extern "C" void kernel_launch(void* const* d_in, const int* in_sizes, int n_in,
                              void* d_out, int out_size, void* d_ws, size_t ws_size,
                              hipStream_t stream) {
    const float* x      = (const float*)d_in[0];
    const float* tau1   = (const float*)d_in[1];
    const float* tau2   = (const float*)d_in[2];
    const float* tau3   = (const float*)d_in[3];
    const float* vth1   = (const float*)d_in[4];
    const float* vth2   = (const float*)d_in[5];
    const float* vth3   = (const float*)d_in[6];
    const float* conv_w = (const float*)d_in[7];
    const float* conv_b = (const float*)d_in[8];
    const float* lin_w  = (const float*)d_in[9];
    const float* lin_b  = (const float*)d_in[10];
    float* out = (float*)d_out;

    const int total  = Bn * FQ;          // 1,048,576 threads
    const int block  = 256;
    const int grid   = total / block;    // 4096 blocks

    lif_net_kernel<<<grid, block, 0, stream>>>(
        x, tau1, tau2, tau3, vth1, vth2, vth3, conv_w, conv_b, lin_w, lin_b, out);
}